// Round 6
// baseline (123.717 us; speedup 1.0000x reference)
//
#include <hip/hip_runtime.h>
#include <math.h>

constexpr int B_ = 8192;
constexpr int T_ = 512;
constexpr int CH = 16;                     // steps per chunk / LDS tile
constexpr int NCH = T_ / CH;               // 32 chunks
constexpr int GRPS = B_ / 64;              // 128 session-groups
constexpr int ROWB = CH * 16 + 16;         // 272 B LDS row (pad)
constexpr size_t PACK_BYTES = (size_t)B_ * T_;          // 4 MB
constexpr size_t PLANE = (size_t)GRPS * NCH * 64;       // 262144 floats per snapshot plane
constexpr int NPLANES = 11;                              // q0..3, c0..3, tsls, expl, oldc
constexpr size_t SNAP_BYTES = PLANE * NPLANES * sizeof(float);   // 11.5 MB
constexpr int CSJ = 26;                                  // 16 M + 4 v + 4 n + lc + run
constexpr size_t CS_BYTES = (size_t)CSJ * NCH * B_ * sizeof(float);   // 27.3 MB

__device__ __forceinline__ float sp_(float x) {
    return fmaxf(x, 0.0f) + log1pf(expf(-fabsf(x)));  // stable softplus
}
__device__ __forceinline__ float sg_(float x) { return 1.0f / (1.0f + expf(-x)); }
__device__ __forceinline__ float clipf(float x, float lo, float hi) { return fminf(fmaxf(x, lo), hi); }
__device__ __forceinline__ float sel(bool c, float a, float b) { return c ? a : b; }

// carry state — all named scalars, statically indexed
struct CS { float q0, q1, q2, q3, c0, c1, c2, c3, tsls, expl; int oldc; };

// One carry step. Shared by all sequential paths -> bit-identical semantics.
__device__ __forceinline__ void step_carry(CS& s, unsigned int byte, float gamma, float decay,
                                           bool& same, bool& i0, bool& i1, bool& i2, bool& i3,
                                           int& cc_out) {
    const int  cc = (int)(byte & 3u);
    const bool rf = (byte & 4u) != 0u;
    const float target = sel(rf, 1.0f, -gamma);          // rv - gamma*(1-rv), rv in {0,1}
    same = (cc == s.oldc);
    s.tsls = sel(same, s.tsls + 1.0f, 0.0f);
    s.expl *= (1.0f - 1e-3f);
    i0 = (cc == 0); i1 = (cc == 1); i2 = (cc == 2); i3 = (cc == 3);
    s.q0 = sel(i0, target, s.q0);  s.c0 += sel(i0, 1.0f, 0.0f);
    s.q1 = sel(i1, target, s.q1);  s.c1 += sel(i1, 1.0f, 0.0f);
    s.q2 = sel(i2, target, s.q2);  s.c2 += sel(i2, 1.0f, 0.0f);
    s.q3 = sel(i3, target, s.q3);  s.c3 += sel(i3, 1.0f, 0.0f);
    const float qm  = 0.25f * ((s.q0 + s.q1) + (s.q2 + s.q3));
    const float omd = (1.0f - s.expl) * decay;
    const float eqd = (s.expl * decay) * qm;
    s.q0 = fmaf(omd, s.q0, eqd);
    s.q1 = fmaf(omd, s.q1, eqd);
    s.q2 = fmaf(omd, s.q2, eqd);
    s.q3 = fmaf(omd, s.q3, eqd);
    s.oldc = cc;
    cc_out = cc;
}

// ---------------- pass 1: compress input to 1 byte/step ----------------
// packed byte index = ((b>>6)*NCH + (t>>4))*1024 + (b&63)*16 + (t&15)
__global__ __launch_bounds__(256) void pack_kernel(const float* __restrict__ in,
                                                   unsigned char* __restrict__ pk) {
    const int tid  = blockIdx.x * 256 + threadIdx.x;      // 0 .. B*T-1
    const int ti   = tid & 15;
    const int lane = (tid >> 4) & 63;
    const int tile = (tid >> 10) & (NCH - 1);
    const int grp  = tid >> 15;
    const int b = (grp << 6) | lane;
    const int t = (tile << 4) | ti;
    const float* base = in + ((size_t)b * T_ + t) * 8;
    const float4 a = *reinterpret_cast<const float4*>(base);
    const float  r = base[4];
    const int cc = a.y > 0.5f ? 1 : (a.z > 0.5f ? 2 : (a.w > 0.5f ? 3 : 0));
    pk[tid] = (unsigned char)(cc | ((r > 0.5f) ? 4 : 0));
}

// ---------------- pass 2a: per-chunk affine summary (fully parallel, B*NCH threads) ----------
// For chunk k of session b, compose q' = M q + v over the 16 steps, plus
// action counts n[4], last-cc (lc) and trailing equal-run length (run).
__global__ __launch_bounds__(64) void chunk_affine(const unsigned char* __restrict__ pk,
                                                   const float* __restrict__ p,
                                                   float* __restrict__ cs) {
    const int l   = threadIdx.x;
    const int bid = blockIdx.x;          // grp*NCH + k
    const int k   = bid & (NCH - 1);
    const int grp = bid >> 5;
    const int b   = grp * 64 + l;

    const float alpha = clipf(sg_(p[3]), 0.01f, 0.99f);
    const float decay = clipf(sg_(p[4]), 0.01f, 0.99f);
    const float gamma = sp_(p[10]);

    // exact expl chain up to step 16k (same rounding as sequential reference)
    float e = alpha;
    const int pre = CH * k;
    for (int i = 0; i < pre; ++i) e *= (1.0f - 1e-3f);

    const uint4 cur = reinterpret_cast<const uint4*>(pk)[(size_t)bid * 64 + l];

    float m[4][4], v[4], n[4];
#pragma unroll
    for (int i = 0; i < 4; ++i) {
#pragma unroll
        for (int j = 0; j < 4; ++j) m[i][j] = (i == j) ? 1.0f : 0.0f;
        v[i] = 0.0f; n[i] = 0.0f;
    }
    int prev = -1, run = 0;

#pragma unroll
    for (int ti = 0; ti < CH; ++ti) {
        const unsigned int word = (ti < 4) ? cur.x : (ti < 8) ? cur.y : (ti < 12) ? cur.z : cur.w;
        const unsigned int byte = (word >> (8 * (ti & 3))) & 0xffu;
        const int  cc = (int)(byte & 3u);
        const bool rf = (byte & 4u) != 0u;
        const float tgt = rf ? 1.0f : -gamma;
        e *= (1.0f - 1e-3f);
        run = (cc == prev) ? (run + 1) : 1;
        prev = cc;
        // P: zero row cc of M, overwrite v[cc] = tgt; count action
#pragma unroll
        for (int i = 0; i < 4; ++i) {
            const bool hit = (i == cc);
            v[i] = hit ? tgt : v[i];
            n[i] += hit ? 1.0f : 0.0f;
#pragma unroll
            for (int j = 0; j < 4; ++j) m[i][j] = hit ? 0.0f : m[i][j];
        }
        // S = decay * [(1-e) I + (e/4) J]
        const float a  = decay * (1.0f - e);
        const float bf = decay * e * 0.25f;
        float csum[4];
#pragma unroll
        for (int j = 0; j < 4; ++j) csum[j] = bf * ((m[0][j] + m[1][j]) + (m[2][j] + m[3][j]));
        const float vs = bf * ((v[0] + v[1]) + (v[2] + v[3]));
#pragma unroll
        for (int i = 0; i < 4; ++i) {
#pragma unroll
            for (int j = 0; j < 4; ++j) m[i][j] = fmaf(a, m[i][j], csum[j]);
            v[i] = fmaf(a, v[i], vs);
        }
    }

    float outv[CSJ];
#pragma unroll
    for (int i = 0; i < 4; ++i)
#pragma unroll
        for (int j = 0; j < 4; ++j) outv[i * 4 + j] = m[i][j];
#pragma unroll
    for (int i = 0; i < 4; ++i) outv[16 + i] = v[i];
#pragma unroll
    for (int i = 0; i < 4; ++i) outv[20 + i] = n[i];
    outv[24] = (float)prev;    // lc
    outv[25] = (float)run;     // trailing run (16 => uniform chunk)
#pragma unroll
    for (int j = 0; j < CSJ; ++j) cs[((size_t)k * CSJ + j) * B_ + b] = outv[j];   // [k][j][B] coalesced
}

// ---------------- pass 2b: boundary prefix over 32 chunks (8192 threads) ----------------
__global__ __launch_bounds__(256) void boundary_prefix(const float* __restrict__ cs,
                                                       const float* __restrict__ p,
                                                       float* __restrict__ snap) {
    const int b   = blockIdx.x * 256 + threadIdx.x;   // session
    const int grp = b >> 6;
    const int l   = b & 63;

    const float prior = clipf(sp_(p[2]), 0.01f, 0.99f);
    const float alpha = clipf(sg_(p[3]), 0.01f, 0.99f);

    float q[4], c[4];
#pragma unroll
    for (int i = 0; i < 4; ++i) { q[i] = prior; c[i] = 0.0f; }
    float e = alpha;
    float ER = 0.0f;         // extended trailing-run length at last processed step
    float lcprev = -1.0f;    // cc of last step of previous chunk
    float tsls = 0.0f;

#pragma unroll 2
    for (int k = 0; k < NCH; ++k) {
        float f[CSJ];
#pragma unroll
        for (int j = 0; j < CSJ; ++j) f[j] = cs[((size_t)k * CSJ + j) * B_ + b];

        // snapshot = state BEFORE chunk k (same semantics/layout as round 5)
        const size_t sb = (size_t)(grp * NCH + k) * 64 + l;
        snap[0 * PLANE + sb] = q[0];  snap[1 * PLANE + sb] = q[1];
        snap[2 * PLANE + sb] = q[2];  snap[3 * PLANE + sb] = q[3];
        snap[4 * PLANE + sb] = c[0];  snap[5 * PLANE + sb] = c[1];
        snap[6 * PLANE + sb] = c[2];  snap[7 * PLANE + sb] = c[3];
        snap[8 * PLANE + sb] = tsls;
        snap[9 * PLANE + sb] = e;
        snap[10 * PLANE + sb] = lcprev;

        // q <- M q + v ; c += n
        float nq[4];
#pragma unroll
        for (int i = 0; i < 4; ++i)
            nq[i] = fmaf(f[i * 4 + 0], q[0],
                    fmaf(f[i * 4 + 1], q[1],
                    fmaf(f[i * 4 + 2], q[2],
                    fmaf(f[i * 4 + 3], q[3], f[16 + i]))));
#pragma unroll
        for (int i = 0; i < 4; ++i) { q[i] = nq[i]; c[i] += f[20 + i]; }

        // tsls recurrence: run extends across uniform chunks with matching value
        const float lc = f[24], run = f[25];
        ER = (run == 16.0f && lc == lcprev) ? (ER + 16.0f) : run;
        tsls = ER - 1.0f;
        lcprev = lc;

        // exact expl chain across the chunk
#pragma unroll
        for (int i = 0; i < CH; ++i) e *= (1.0f - 1e-3f);
    }
}

// ---------------- pass 3: per-chunk logits, fully parallel (unchanged from round 5) ----------
__global__ __launch_bounds__(64) void chunk_logits(const unsigned char* __restrict__ pk,
                                                   const float* __restrict__ p,
                                                   const float* __restrict__ snap,
                                                   float* __restrict__ out) {
    __shared__ unsigned char lds[64 * ROWB];
    const int l   = threadIdx.x;
    const int bid = blockIdx.x;          // = grp*NCH + k
    const int k   = bid & (NCH - 1);
    const int grp = bid >> 5;            // NCH == 32

    const float beta_r = clipf(sp_(p[0]), 0.01f, 20.0f);
    const float lapse  = clipf(sg_(p[1]), 0.01f, 0.99f);
    const float decay  = clipf(sg_(p[4]), 0.01f, 0.99f);
    const float ab1    = p[5];
    const float ab2    = p[6];
    const float pers   = sp_(p[7]);
    const float sw     = p[8];
    const float gamma  = sp_(p[10]);
    const float temp   = clipf(sp_(p[11]) + 1e-6f, 1e-6f, 100.0f);
    const float beta_p = sp_(p[12]);
    const float brt = beta_r / temp;
    const float l4  = lapse * 0.25f;
    const float oml = 1.0f - lapse;

    const size_t sb = (size_t)bid * 64 + l;
    CS s;
    s.q0 = snap[0 * PLANE + sb];  s.q1 = snap[1 * PLANE + sb];
    s.q2 = snap[2 * PLANE + sb];  s.q3 = snap[3 * PLANE + sb];
    s.c0 = snap[4 * PLANE + sb];  s.c1 = snap[5 * PLANE + sb];
    s.c2 = snap[6 * PLANE + sb];  s.c3 = snap[7 * PLANE + sb];
    s.tsls = snap[8 * PLANE + sb];
    s.expl = snap[9 * PLANE + sb];
    s.oldc = (int)snap[10 * PLANE + sb];

    const uint4 cur = reinterpret_cast<const uint4*>(pk)[(size_t)bid * 64 + l];

#pragma unroll
    for (int ti = 0; ti < CH; ++ti) {
        const unsigned int word = (ti < 4) ? cur.x : (ti < 8) ? cur.y : (ti < 12) ? cur.z : cur.w;
        const unsigned int byte = (word >> (8 * (ti & 3))) & 0xffu;
        const int prev = s.oldc;
        bool same, i0, i1, i2, i3; int cc;
        step_carry(s, byte, gamma, decay, same, i0, i1, i2, i3, cc);

        const float s0 = fmaf(brt, s.q0, beta_p * __logf(1.0f + s.c0));
        const float s1 = fmaf(brt, s.q1, beta_p * __logf(1.0f + s.c1));
        const float s2 = fmaf(brt, s.q2, beta_p * __logf(1.0f + s.c2));
        const float s3 = fmaf(brt, s.q3, beta_p * __logf(1.0f + s.c3));
        const float m  = fmaxf(fmaxf(s0, s1), fmaxf(s2, s3));
        const float e0 = __expf(s0 - m);
        const float e1 = __expf(s1 - m);
        const float e2 = __expf(s2 - m);
        const float e3 = __expf(s3 - m);
        const float iz = oml / ((e0 + e1) + (e2 + e3));

        float l0 = __logf(fmaf(e0, iz, l4));
        float l1 = __logf(fmaf(e1, iz, l4));
        float l2 = __logf(fmaf(e2, iz, l4));
        float l3 = __logf(fmaf(e3, iz, l4));

        const float bcc = sel(same, pers, sw) + __logf(s.tsls + 1.0f);
        const int cc2 = cc ^ 2;
        l0 += sel(i0, bcc, 0.0f) + sel(prev == 0, ab1, 0.0f) + sel(cc2 == 0, ab2, 0.0f);
        l1 += sel(i1, bcc, 0.0f) + sel(prev == 1, ab1, 0.0f) + sel(cc2 == 1, ab2, 0.0f);
        l2 += sel(i2, bcc, 0.0f) + sel(prev == 2, ab1, 0.0f) + sel(cc2 == 2, ab2, 0.0f);
        l3 += sel(i3, bcc, 0.0f) + sel(prev == 3, ab1, 0.0f) + sel(cc2 == 3, ab2, 0.0f);

        *reinterpret_cast<float4*>(&lds[l * ROWB + ti * 16]) = make_float4(l0, l1, l2, l3);
    }

    __syncthreads();
    float4* __restrict__ out4 = reinterpret_cast<float4*>(out);
#pragma unroll
    for (int pp = 0; pp < 16; ++pp) {
        const int ss = pp * 4 + (l >> 4);    // session within group
        const int st = l & 15;               // step within chunk
        const float4 v = *reinterpret_cast<const float4*>(&lds[ss * ROWB + st * 16]);
        out4[((size_t)(grp * 64 + ss)) * T_ + k * CH + st] = v;   // coalesced wave-store
    }
}

// ---------------- fallback A: round-5 sequential carry (ws >= pk+snap) ----------------
__global__ __launch_bounds__(64, 1) void seq_carry(const unsigned char* __restrict__ pk,
                                                   const float* __restrict__ p,
                                                   float* __restrict__ snap) {
    const int l   = threadIdx.x;
    const int grp = blockIdx.x;

    const float prior = clipf(sp_(p[2]), 0.01f, 0.99f);
    const float alpha = clipf(sg_(p[3]), 0.01f, 0.99f);
    const float decay = clipf(sg_(p[4]), 0.01f, 0.99f);
    const float gamma = sp_(p[10]);

    CS s;
    s.q0 = s.q1 = s.q2 = s.q3 = prior;
    s.c0 = s.c1 = s.c2 = s.c3 = 0.0f;
    s.tsls = 0.0f; s.expl = alpha; s.oldc = -1;

    const uint4* __restrict__ pkt =
        reinterpret_cast<const uint4*>(pk + (size_t)grp * (NCH * 1024)) + l;

    uint4 cur = pkt[0];
    for (int k = 0; k < NCH; ++k) {
        const size_t sb = (size_t)(grp * NCH + k) * 64 + l;
        snap[0 * PLANE + sb] = s.q0;  snap[1 * PLANE + sb] = s.q1;
        snap[2 * PLANE + sb] = s.q2;  snap[3 * PLANE + sb] = s.q3;
        snap[4 * PLANE + sb] = s.c0;  snap[5 * PLANE + sb] = s.c1;
        snap[6 * PLANE + sb] = s.c2;  snap[7 * PLANE + sb] = s.c3;
        snap[8 * PLANE + sb] = s.tsls;
        snap[9 * PLANE + sb] = s.expl;
        snap[10 * PLANE + sb] = (float)s.oldc;

        const uint4 nxt = pkt[(k + 1 < NCH ? k + 1 : k) * 64];
#pragma unroll
        for (int ti = 0; ti < CH; ++ti) {
            const unsigned int word = (ti < 4) ? cur.x : (ti < 8) ? cur.y : (ti < 12) ? cur.z : cur.w;
            const unsigned int byte = (word >> (8 * (ti & 3))) & 0xffu;
            bool same, i0, i1, i2, i3; int cc;
            step_carry(s, byte, gamma, decay, same, i0, i1, i2, i3, cc);
        }
        cur = nxt;
    }
}

// ---------------- fallback B: monolithic packed scan (ws >= 4MB only) ----------------
__global__ __launch_bounds__(64, 1) void castro_scan_packed(
    const unsigned char* __restrict__ pk, const float* __restrict__ p, float* __restrict__ out)
{
    __shared__ unsigned char lds[64 * ROWB];
    const int l = threadIdx.x, blk = blockIdx.x;
    const float beta_r = clipf(sp_(p[0]), 0.01f, 20.0f);
    const float lapse  = clipf(sg_(p[1]), 0.01f, 0.99f);
    const float prior  = clipf(sp_(p[2]), 0.01f, 0.99f);
    const float alpha  = clipf(sg_(p[3]), 0.01f, 0.99f);
    const float decay  = clipf(sg_(p[4]), 0.01f, 0.99f);
    const float ab1 = p[5], ab2 = p[6];
    const float pers = sp_(p[7]), sw = p[8];
    const float gamma = sp_(p[10]);
    const float temp = clipf(sp_(p[11]) + 1e-6f, 1e-6f, 100.0f);
    const float beta_p = sp_(p[12]);
    const float brt = beta_r / temp, l4 = lapse * 0.25f, oml = 1.0f - lapse;
    CS s; s.q0 = s.q1 = s.q2 = s.q3 = prior;
    s.c0 = s.c1 = s.c2 = s.c3 = 0.0f; s.tsls = 0.0f; s.expl = alpha; s.oldc = -1;
    const uint4* pkt = reinterpret_cast<const uint4*>(pk + (size_t)blk * (NCH * 1024)) + l;
    float4* out4 = reinterpret_cast<float4*>(out);
    uint4 cur = pkt[0];
    for (int k = 0; k < NCH; ++k) {
        const uint4 nxt = pkt[(k + 1 < NCH ? k + 1 : k) * 64];
#pragma unroll
        for (int ti = 0; ti < CH; ++ti) {
            const unsigned int word = (ti < 4) ? cur.x : (ti < 8) ? cur.y : (ti < 12) ? cur.z : cur.w;
            const unsigned int byte = (word >> (8 * (ti & 3))) & 0xffu;
            const int prev = s.oldc;
            bool same, i0, i1, i2, i3; int cc;
            step_carry(s, byte, gamma, decay, same, i0, i1, i2, i3, cc);
            const float s0 = fmaf(brt, s.q0, beta_p * __logf(1.0f + s.c0));
            const float s1 = fmaf(brt, s.q1, beta_p * __logf(1.0f + s.c1));
            const float s2 = fmaf(brt, s.q2, beta_p * __logf(1.0f + s.c2));
            const float s3 = fmaf(brt, s.q3, beta_p * __logf(1.0f + s.c3));
            const float m = fmaxf(fmaxf(s0, s1), fmaxf(s2, s3));
            const float e0 = __expf(s0 - m), e1 = __expf(s1 - m);
            const float e2 = __expf(s2 - m), e3 = __expf(s3 - m);
            const float iz = oml / ((e0 + e1) + (e2 + e3));
            float l0 = __logf(fmaf(e0, iz, l4)), l1 = __logf(fmaf(e1, iz, l4));
            float l2 = __logf(fmaf(e2, iz, l4)), l3 = __logf(fmaf(e3, iz, l4));
            const float bcc = sel(same, pers, sw) + __logf(s.tsls + 1.0f);
            const int cc2 = cc ^ 2;
            l0 += sel(i0, bcc, 0.f) + sel(prev == 0, ab1, 0.f) + sel(cc2 == 0, ab2, 0.f);
            l1 += sel(i1, bcc, 0.f) + sel(prev == 1, ab1, 0.f) + sel(cc2 == 1, ab2, 0.f);
            l2 += sel(i2, bcc, 0.f) + sel(prev == 2, ab1, 0.f) + sel(cc2 == 2, ab2, 0.f);
            l3 += sel(i3, bcc, 0.f) + sel(prev == 3, ab1, 0.f) + sel(cc2 == 3, ab2, 0.f);
            *reinterpret_cast<float4*>(&lds[l * ROWB + ti * 16]) = make_float4(l0, l1, l2, l3);
        }
        __syncthreads();
#pragma unroll
        for (int pp = 0; pp < 16; ++pp) {
            const int ss = pp * 4 + (l >> 4);
            const int st = l & 15;
            const float4 v = *reinterpret_cast<const float4*>(&lds[ss * ROWB + st * 16]);
            out4[((size_t)(blk * 64 + ss)) * T_ + k * CH + st] = v;
        }
        __syncthreads();
        cur = nxt;
    }
}

extern "C" void kernel_launch(void* const* d_in, const int* in_sizes, int n_in,
                              void* d_out, int out_size, void* d_ws, size_t ws_size,
                              hipStream_t stream) {
    const float* inputs = (const float*)d_in[0];   // [8192, 512, 8] f32
    const float* params = (const float*)d_in[1];   // [13] f32
    float* out = (float*)d_out;                    // [8192, 512, 4] f32

    if (ws_size >= PACK_BYTES + SNAP_BYTES + CS_BYTES) {
        unsigned char* pk = (unsigned char*)d_ws;
        float* snap = (float*)((char*)d_ws + PACK_BYTES);
        float* cs   = (float*)((char*)d_ws + PACK_BYTES + SNAP_BYTES);
        pack_kernel<<<dim3((B_ * T_) / 256), dim3(256), 0, stream>>>(inputs, pk);
        chunk_affine<<<dim3(GRPS * NCH), dim3(64), 0, stream>>>(pk, params, cs);
        boundary_prefix<<<dim3(B_ / 256), dim3(256), 0, stream>>>(cs, params, snap);
        chunk_logits<<<dim3(GRPS * NCH), dim3(64), 0, stream>>>(pk, params, snap, out);
    } else if (ws_size >= PACK_BYTES + SNAP_BYTES) {
        unsigned char* pk = (unsigned char*)d_ws;
        float* snap = (float*)((char*)d_ws + PACK_BYTES);
        pack_kernel<<<dim3((B_ * T_) / 256), dim3(256), 0, stream>>>(inputs, pk);
        seq_carry<<<dim3(GRPS), dim3(64), 0, stream>>>(pk, params, snap);
        chunk_logits<<<dim3(GRPS * NCH), dim3(64), 0, stream>>>(pk, params, snap, out);
    } else if (ws_size >= PACK_BYTES) {
        unsigned char* pk = (unsigned char*)d_ws;
        pack_kernel<<<dim3((B_ * T_) / 256), dim3(256), 0, stream>>>(inputs, pk);
        castro_scan_packed<<<dim3(GRPS), dim3(64), 0, stream>>>(pk, params, out);
    }
}

// Round 7
// 117.568 us; speedup vs baseline: 1.0523x; 1.0523x over previous
//
#include <hip/hip_runtime.h>
#include <math.h>

constexpr int B_ = 8192;
constexpr int T_ = 512;
constexpr int CH = 16;                     // steps per chunk / LDS tile
constexpr int NCH = T_ / CH;               // 32 chunks
constexpr int GRPS = B_ / 64;              // 128 session-groups
constexpr int ROWB = CH * 16 + 16;         // 272 B LDS row (pad)
constexpr size_t PACK_BYTES = (size_t)B_ * T_;          // 4 MB
constexpr size_t PLANE = (size_t)GRPS * NCH * 64;       // 262144 floats per snapshot plane
constexpr int NPLANES = 11;                              // q0..3, c0..3, tsls, expl, oldc
constexpr size_t SNAP_BYTES = PLANE * NPLANES * sizeof(float);   // 11.5 MB
constexpr int CSJ = 26;                                  // 16 M + 4 v + 4 n + lc + run
constexpr size_t CS_BYTES = (size_t)CSJ * NCH * B_ * sizeof(float);   // 27.3 MB

__device__ __forceinline__ float sp_(float x) {
    return fmaxf(x, 0.0f) + log1pf(expf(-fabsf(x)));  // stable softplus
}
__device__ __forceinline__ float sg_(float x) { return 1.0f / (1.0f + expf(-x)); }
__device__ __forceinline__ float clipf(float x, float lo, float hi) { return fminf(fmaxf(x, lo), hi); }
__device__ __forceinline__ float sel(bool c, float a, float b) { return c ? a : b; }

// carry state — all named scalars, statically indexed
struct CS { float q0, q1, q2, q3, c0, c1, c2, c3, tsls, expl; int oldc; };

// One carry step. Shared by all sequential paths -> bit-identical semantics.
__device__ __forceinline__ void step_carry(CS& s, unsigned int byte, float gamma, float decay,
                                           bool& same, bool& i0, bool& i1, bool& i2, bool& i3,
                                           int& cc_out) {
    const int  cc = (int)(byte & 3u);
    const bool rf = (byte & 4u) != 0u;
    const float target = sel(rf, 1.0f, -gamma);          // rv - gamma*(1-rv), rv in {0,1}
    same = (cc == s.oldc);
    s.tsls = sel(same, s.tsls + 1.0f, 0.0f);
    s.expl *= (1.0f - 1e-3f);
    i0 = (cc == 0); i1 = (cc == 1); i2 = (cc == 2); i3 = (cc == 3);
    s.q0 = sel(i0, target, s.q0);  s.c0 += sel(i0, 1.0f, 0.0f);
    s.q1 = sel(i1, target, s.q1);  s.c1 += sel(i1, 1.0f, 0.0f);
    s.q2 = sel(i2, target, s.q2);  s.c2 += sel(i2, 1.0f, 0.0f);
    s.q3 = sel(i3, target, s.q3);  s.c3 += sel(i3, 1.0f, 0.0f);
    const float qm  = 0.25f * ((s.q0 + s.q1) + (s.q2 + s.q3));
    const float omd = (1.0f - s.expl) * decay;
    const float eqd = (s.expl * decay) * qm;
    s.q0 = fmaf(omd, s.q0, eqd);
    s.q1 = fmaf(omd, s.q1, eqd);
    s.q2 = fmaf(omd, s.q2, eqd);
    s.q3 = fmaf(omd, s.q3, eqd);
    s.oldc = cc;
    cc_out = cc;
}

// ================= PRIMARY PATH =================

// ---- pass 1 (fused): read raw input per (session,chunk), emit packed bytes + affine summary ----
// thread = (bid = grp*NCH + k, lane = sess). Reads 16 steps x (float4 + scalar r).
// Every 64B line is consumed by exactly one thread (steps 2t,2t+1 share a line; r hits same lines).
__global__ __launch_bounds__(64, 4) void fused_pack_affine(
    const float* __restrict__ in, const float* __restrict__ p,
    unsigned char* __restrict__ pk, float* __restrict__ cs)
{
    const int lane = threadIdx.x;
    const int bid  = blockIdx.x;          // grp*NCH + k
    const int k    = bid & (NCH - 1);
    const int grp  = bid >> 5;
    const int b    = grp * 64 + lane;

    const float alpha = clipf(sg_(p[3]), 0.01f, 0.99f);
    const float decay = clipf(sg_(p[4]), 0.01f, 0.99f);
    const float gamma = sp_(p[10]);

    // exact expl chain up to step 16k (same rounding as sequential reference)
    float e = alpha;
    const int pre = CH * k;
    for (int i = 0; i < pre; ++i) e *= (1.0f - 1e-3f);

    const float*  basef = in + ((size_t)b * T_ + (size_t)k * CH) * 8;
    const float4* ip    = reinterpret_cast<const float4*>(basef);

    // prefetch all 16 action float4s (static indices)
    float4 av[CH];
#pragma unroll
    for (int ti = 0; ti < CH; ++ti) av[ti] = ip[2 * ti];

    float m[4][4], v[4], n[4];
#pragma unroll
    for (int i = 0; i < 4; ++i) {
#pragma unroll
        for (int j = 0; j < 4; ++j) m[i][j] = (i == j) ? 1.0f : 0.0f;
        v[i] = 0.0f; n[i] = 0.0f;
    }
    int prev = -1, run = 0;
    unsigned int w0 = 0, w1 = 0, w2 = 0, w3 = 0;

#pragma unroll
    for (int ti = 0; ti < CH; ++ti) {
        const float4 a = av[ti];
        const float  r = basef[ti * 8 + 4];    // L1 hit (line fetched by av load)
        const int  cc = a.y > 0.5f ? 1 : (a.z > 0.5f ? 2 : (a.w > 0.5f ? 3 : 0));
        const bool rf = (r > 0.5f);
        const unsigned int byte = (unsigned int)cc | (rf ? 4u : 0u);
        if      (ti < 4)  w0 |= byte << (8 * ti);
        else if (ti < 8)  w1 |= byte << (8 * (ti - 4));
        else if (ti < 12) w2 |= byte << (8 * (ti - 8));
        else              w3 |= byte << (8 * (ti - 12));

        const float tgt = rf ? 1.0f : -gamma;
        e *= (1.0f - 1e-3f);
        run = (cc == prev) ? (run + 1) : 1;
        prev = cc;
        // P: zero row cc of M, overwrite v[cc] = tgt; count action
#pragma unroll
        for (int i = 0; i < 4; ++i) {
            const bool hit = (i == cc);
            v[i] = hit ? tgt : v[i];
            n[i] += hit ? 1.0f : 0.0f;
#pragma unroll
            for (int j = 0; j < 4; ++j) m[i][j] = hit ? 0.0f : m[i][j];
        }
        // S = decay * [(1-e) I + (e/4) J]
        const float aa = decay * (1.0f - e);
        const float bf = decay * e * 0.25f;
        float csum[4];
#pragma unroll
        for (int j = 0; j < 4; ++j) csum[j] = bf * ((m[0][j] + m[1][j]) + (m[2][j] + m[3][j]));
        const float vs = bf * ((v[0] + v[1]) + (v[2] + v[3]));
#pragma unroll
        for (int i = 0; i < 4; ++i) {
#pragma unroll
            for (int j = 0; j < 4; ++j) m[i][j] = fmaf(aa, m[i][j], csum[j]);
            v[i] = fmaf(aa, v[i], vs);
        }
    }

    // packed codes: same layout chunk_logits expects (uint4 per (bid,lane))
    reinterpret_cast<uint4*>(pk)[(size_t)bid * 64 + lane] = make_uint4(w0, w1, w2, w3);

    float outv[CSJ];
#pragma unroll
    for (int i = 0; i < 4; ++i)
#pragma unroll
        for (int j = 0; j < 4; ++j) outv[i * 4 + j] = m[i][j];
#pragma unroll
    for (int i = 0; i < 4; ++i) outv[16 + i] = v[i];
#pragma unroll
    for (int i = 0; i < 4; ++i) outv[20 + i] = n[i];
    outv[24] = (float)prev;    // lc
    outv[25] = (float)run;     // trailing run (16 => uniform chunk)
#pragma unroll
    for (int j = 0; j < CSJ; ++j) cs[((size_t)k * CSJ + j) * B_ + b] = outv[j];   // coalesced
}

// ---- pass 2: boundary prefix, 128 blocks x 64 thr, depth-2 pipelined loads ----
__global__ __launch_bounds__(64, 1) void boundary_prefix2(const float* __restrict__ cs,
                                                          const float* __restrict__ p,
                                                          float* __restrict__ snap) {
    const int b   = blockIdx.x * 64 + threadIdx.x;   // session; 128 blocks
    const int grp = b >> 6;
    const int l   = b & 63;

    const float prior = clipf(sp_(p[2]), 0.01f, 0.99f);
    const float alpha = clipf(sg_(p[3]), 0.01f, 0.99f);

    float q[4], c[4];
#pragma unroll
    for (int i = 0; i < 4; ++i) { q[i] = prior; c[i] = 0.0f; }
    float e = alpha;
    float ER = 0.0f;
    float lcprev = -1.0f;
    float tsls = 0.0f;

    float buf[3][CSJ];   // depth-2 pipeline; all indices compile-time under full unroll
#pragma unroll
    for (int j = 0; j < CSJ; ++j) buf[0][j] = cs[((size_t)(0 * CSJ + j)) * B_ + b];
#pragma unroll
    for (int j = 0; j < CSJ; ++j) buf[1][j] = cs[((size_t)(1 * CSJ + j)) * B_ + b];

#pragma unroll
    for (int k = 0; k < NCH; ++k) {
        // issue loads for chunk k+2 (consumed two iterations later)
        if (k + 2 < NCH) {
#pragma unroll
            for (int j = 0; j < CSJ; ++j)
                buf[(k + 2) % 3][j] = cs[((size_t)((k + 2) * CSJ + j)) * B_ + b];
        }

        // snapshot = state BEFORE chunk k (layout consumed by chunk_logits)
        const size_t sb = (size_t)(grp * NCH + k) * 64 + l;
        snap[0 * PLANE + sb] = q[0];  snap[1 * PLANE + sb] = q[1];
        snap[2 * PLANE + sb] = q[2];  snap[3 * PLANE + sb] = q[3];
        snap[4 * PLANE + sb] = c[0];  snap[5 * PLANE + sb] = c[1];
        snap[6 * PLANE + sb] = c[2];  snap[7 * PLANE + sb] = c[3];
        snap[8 * PLANE + sb] = tsls;
        snap[9 * PLANE + sb] = e;
        snap[10 * PLANE + sb] = lcprev;

        // q <- M q + v ; c += n   (same FLOP order as round 6)
        float nq[4];
#pragma unroll
        for (int i = 0; i < 4; ++i)
            nq[i] = fmaf(buf[k % 3][i * 4 + 0], q[0],
                    fmaf(buf[k % 3][i * 4 + 1], q[1],
                    fmaf(buf[k % 3][i * 4 + 2], q[2],
                    fmaf(buf[k % 3][i * 4 + 3], q[3], buf[k % 3][16 + i]))));
#pragma unroll
        for (int i = 0; i < 4; ++i) { q[i] = nq[i]; c[i] += buf[k % 3][20 + i]; }

        const float lc = buf[k % 3][24], run = buf[k % 3][25];
        ER = (run == 16.0f && lc == lcprev) ? (ER + 16.0f) : run;
        tsls = ER - 1.0f;
        lcprev = lc;

#pragma unroll
        for (int i = 0; i < CH; ++i) e *= (1.0f - 1e-3f);
    }
}

// ---- pass 3: per-chunk logits, fully parallel (unchanged, proven) ----
__global__ __launch_bounds__(64) void chunk_logits(const unsigned char* __restrict__ pk,
                                                   const float* __restrict__ p,
                                                   const float* __restrict__ snap,
                                                   float* __restrict__ out) {
    __shared__ unsigned char lds[64 * ROWB];
    const int l   = threadIdx.x;
    const int bid = blockIdx.x;          // = grp*NCH + k
    const int k   = bid & (NCH - 1);
    const int grp = bid >> 5;            // NCH == 32

    const float beta_r = clipf(sp_(p[0]), 0.01f, 20.0f);
    const float lapse  = clipf(sg_(p[1]), 0.01f, 0.99f);
    const float decay  = clipf(sg_(p[4]), 0.01f, 0.99f);
    const float ab1    = p[5];
    const float ab2    = p[6];
    const float pers   = sp_(p[7]);
    const float sw     = p[8];
    const float gamma  = sp_(p[10]);
    const float temp   = clipf(sp_(p[11]) + 1e-6f, 1e-6f, 100.0f);
    const float beta_p = sp_(p[12]);
    const float brt = beta_r / temp;
    const float l4  = lapse * 0.25f;
    const float oml = 1.0f - lapse;

    const size_t sb = (size_t)bid * 64 + l;
    CS s;
    s.q0 = snap[0 * PLANE + sb];  s.q1 = snap[1 * PLANE + sb];
    s.q2 = snap[2 * PLANE + sb];  s.q3 = snap[3 * PLANE + sb];
    s.c0 = snap[4 * PLANE + sb];  s.c1 = snap[5 * PLANE + sb];
    s.c2 = snap[6 * PLANE + sb];  s.c3 = snap[7 * PLANE + sb];
    s.tsls = snap[8 * PLANE + sb];
    s.expl = snap[9 * PLANE + sb];
    s.oldc = (int)snap[10 * PLANE + sb];

    const uint4 cur = reinterpret_cast<const uint4*>(pk)[(size_t)bid * 64 + l];

#pragma unroll
    for (int ti = 0; ti < CH; ++ti) {
        const unsigned int word = (ti < 4) ? cur.x : (ti < 8) ? cur.y : (ti < 12) ? cur.z : cur.w;
        const unsigned int byte = (word >> (8 * (ti & 3))) & 0xffu;
        const int prev = s.oldc;
        bool same, i0, i1, i2, i3; int cc;
        step_carry(s, byte, gamma, decay, same, i0, i1, i2, i3, cc);

        const float s0 = fmaf(brt, s.q0, beta_p * __logf(1.0f + s.c0));
        const float s1 = fmaf(brt, s.q1, beta_p * __logf(1.0f + s.c1));
        const float s2 = fmaf(brt, s.q2, beta_p * __logf(1.0f + s.c2));
        const float s3 = fmaf(brt, s.q3, beta_p * __logf(1.0f + s.c3));
        const float m  = fmaxf(fmaxf(s0, s1), fmaxf(s2, s3));
        const float e0 = __expf(s0 - m);
        const float e1 = __expf(s1 - m);
        const float e2 = __expf(s2 - m);
        const float e3 = __expf(s3 - m);
        const float iz = oml / ((e0 + e1) + (e2 + e3));

        float l0 = __logf(fmaf(e0, iz, l4));
        float l1 = __logf(fmaf(e1, iz, l4));
        float l2 = __logf(fmaf(e2, iz, l4));
        float l3 = __logf(fmaf(e3, iz, l4));

        const float bcc = sel(same, pers, sw) + __logf(s.tsls + 1.0f);
        const int cc2 = cc ^ 2;
        l0 += sel(i0, bcc, 0.0f) + sel(prev == 0, ab1, 0.0f) + sel(cc2 == 0, ab2, 0.0f);
        l1 += sel(i1, bcc, 0.0f) + sel(prev == 1, ab1, 0.0f) + sel(cc2 == 1, ab2, 0.0f);
        l2 += sel(i2, bcc, 0.0f) + sel(prev == 2, ab1, 0.0f) + sel(cc2 == 2, ab2, 0.0f);
        l3 += sel(i3, bcc, 0.0f) + sel(prev == 3, ab1, 0.0f) + sel(cc2 == 3, ab2, 0.0f);

        *reinterpret_cast<float4*>(&lds[l * ROWB + ti * 16]) = make_float4(l0, l1, l2, l3);
    }

    __syncthreads();
    float4* __restrict__ out4 = reinterpret_cast<float4*>(out);
#pragma unroll
    for (int pp = 0; pp < 16; ++pp) {
        const int ss = pp * 4 + (l >> 4);    // session within group
        const int st = l & 15;               // step within chunk
        const float4 v = *reinterpret_cast<const float4*>(&lds[ss * ROWB + st * 16]);
        out4[((size_t)(grp * 64 + ss)) * T_ + k * CH + st] = v;   // coalesced wave-store
    }
}

// ================= FALLBACK PATHS =================

__global__ __launch_bounds__(256) void pack_kernel(const float* __restrict__ in,
                                                   unsigned char* __restrict__ pk) {
    const int tid  = blockIdx.x * 256 + threadIdx.x;      // 0 .. B*T-1
    const int ti   = tid & 15;
    const int lane = (tid >> 4) & 63;
    const int tile = (tid >> 10) & (NCH - 1);
    const int grp  = tid >> 15;
    const int b = (grp << 6) | lane;
    const int t = (tile << 4) | ti;
    const float* base = in + ((size_t)b * T_ + t) * 8;
    const float4 a = *reinterpret_cast<const float4*>(base);
    const float  r = base[4];
    const int cc = a.y > 0.5f ? 1 : (a.z > 0.5f ? 2 : (a.w > 0.5f ? 3 : 0));
    pk[tid] = (unsigned char)(cc | ((r > 0.5f) ? 4 : 0));
}

__global__ __launch_bounds__(64, 1) void seq_carry(const unsigned char* __restrict__ pk,
                                                   const float* __restrict__ p,
                                                   float* __restrict__ snap) {
    const int l   = threadIdx.x;
    const int grp = blockIdx.x;

    const float prior = clipf(sp_(p[2]), 0.01f, 0.99f);
    const float alpha = clipf(sg_(p[3]), 0.01f, 0.99f);
    const float decay = clipf(sg_(p[4]), 0.01f, 0.99f);
    const float gamma = sp_(p[10]);

    CS s;
    s.q0 = s.q1 = s.q2 = s.q3 = prior;
    s.c0 = s.c1 = s.c2 = s.c3 = 0.0f;
    s.tsls = 0.0f; s.expl = alpha; s.oldc = -1;

    const uint4* __restrict__ pkt =
        reinterpret_cast<const uint4*>(pk + (size_t)grp * (NCH * 1024)) + l;

    uint4 cur = pkt[0];
    for (int k = 0; k < NCH; ++k) {
        const size_t sb = (size_t)(grp * NCH + k) * 64 + l;
        snap[0 * PLANE + sb] = s.q0;  snap[1 * PLANE + sb] = s.q1;
        snap[2 * PLANE + sb] = s.q2;  snap[3 * PLANE + sb] = s.q3;
        snap[4 * PLANE + sb] = s.c0;  snap[5 * PLANE + sb] = s.c1;
        snap[6 * PLANE + sb] = s.c2;  snap[7 * PLANE + sb] = s.c3;
        snap[8 * PLANE + sb] = s.tsls;
        snap[9 * PLANE + sb] = s.expl;
        snap[10 * PLANE + sb] = (float)s.oldc;

        const uint4 nxt = pkt[(k + 1 < NCH ? k + 1 : k) * 64];
#pragma unroll
        for (int ti = 0; ti < CH; ++ti) {
            const unsigned int word = (ti < 4) ? cur.x : (ti < 8) ? cur.y : (ti < 12) ? cur.z : cur.w;
            const unsigned int byte = (word >> (8 * (ti & 3))) & 0xffu;
            bool same, i0, i1, i2, i3; int cc;
            step_carry(s, byte, gamma, decay, same, i0, i1, i2, i3, cc);
        }
        cur = nxt;
    }
}

__global__ __launch_bounds__(64, 1) void castro_scan_packed(
    const unsigned char* __restrict__ pk, const float* __restrict__ p, float* __restrict__ out)
{
    __shared__ unsigned char lds[64 * ROWB];
    const int l = threadIdx.x, blk = blockIdx.x;
    const float beta_r = clipf(sp_(p[0]), 0.01f, 20.0f);
    const float lapse  = clipf(sg_(p[1]), 0.01f, 0.99f);
    const float prior  = clipf(sp_(p[2]), 0.01f, 0.99f);
    const float alpha  = clipf(sg_(p[3]), 0.01f, 0.99f);
    const float decay  = clipf(sg_(p[4]), 0.01f, 0.99f);
    const float ab1 = p[5], ab2 = p[6];
    const float pers = sp_(p[7]), sw = p[8];
    const float gamma = sp_(p[10]);
    const float temp = clipf(sp_(p[11]) + 1e-6f, 1e-6f, 100.0f);
    const float beta_p = sp_(p[12]);
    const float brt = beta_r / temp, l4 = lapse * 0.25f, oml = 1.0f - lapse;
    CS s; s.q0 = s.q1 = s.q2 = s.q3 = prior;
    s.c0 = s.c1 = s.c2 = s.c3 = 0.0f; s.tsls = 0.0f; s.expl = alpha; s.oldc = -1;
    const uint4* pkt = reinterpret_cast<const uint4*>(pk + (size_t)blk * (NCH * 1024)) + l;
    float4* out4 = reinterpret_cast<float4*>(out);
    uint4 cur = pkt[0];
    for (int k = 0; k < NCH; ++k) {
        const uint4 nxt = pkt[(k + 1 < NCH ? k + 1 : k) * 64];
#pragma unroll
        for (int ti = 0; ti < CH; ++ti) {
            const unsigned int word = (ti < 4) ? cur.x : (ti < 8) ? cur.y : (ti < 12) ? cur.z : cur.w;
            const unsigned int byte = (word >> (8 * (ti & 3))) & 0xffu;
            const int prev = s.oldc;
            bool same, i0, i1, i2, i3; int cc;
            step_carry(s, byte, gamma, decay, same, i0, i1, i2, i3, cc);
            const float s0 = fmaf(brt, s.q0, beta_p * __logf(1.0f + s.c0));
            const float s1 = fmaf(brt, s.q1, beta_p * __logf(1.0f + s.c1));
            const float s2 = fmaf(brt, s.q2, beta_p * __logf(1.0f + s.c2));
            const float s3 = fmaf(brt, s.q3, beta_p * __logf(1.0f + s.c3));
            const float m = fmaxf(fmaxf(s0, s1), fmaxf(s2, s3));
            const float e0 = __expf(s0 - m), e1 = __expf(s1 - m);
            const float e2 = __expf(s2 - m), e3 = __expf(s3 - m);
            const float iz = oml / ((e0 + e1) + (e2 + e3));
            float l0 = __logf(fmaf(e0, iz, l4)), l1 = __logf(fmaf(e1, iz, l4));
            float l2 = __logf(fmaf(e2, iz, l4)), l3 = __logf(fmaf(e3, iz, l4));
            const float bcc = sel(same, pers, sw) + __logf(s.tsls + 1.0f);
            const int cc2 = cc ^ 2;
            l0 += sel(i0, bcc, 0.f) + sel(prev == 0, ab1, 0.f) + sel(cc2 == 0, ab2, 0.f);
            l1 += sel(i1, bcc, 0.f) + sel(prev == 1, ab1, 0.f) + sel(cc2 == 1, ab2, 0.f);
            l2 += sel(i2, bcc, 0.f) + sel(prev == 2, ab1, 0.f) + sel(cc2 == 2, ab2, 0.f);
            l3 += sel(i3, bcc, 0.f) + sel(prev == 3, ab1, 0.f) + sel(cc2 == 3, ab2, 0.f);
            *reinterpret_cast<float4*>(&lds[l * ROWB + ti * 16]) = make_float4(l0, l1, l2, l3);
        }
        __syncthreads();
#pragma unroll
        for (int pp = 0; pp < 16; ++pp) {
            const int ss = pp * 4 + (l >> 4);
            const int st = l & 15;
            const float4 v = *reinterpret_cast<const float4*>(&lds[ss * ROWB + st * 16]);
            out4[((size_t)(blk * 64 + ss)) * T_ + k * CH + st] = v;
        }
        __syncthreads();
        cur = nxt;
    }
}

extern "C" void kernel_launch(void* const* d_in, const int* in_sizes, int n_in,
                              void* d_out, int out_size, void* d_ws, size_t ws_size,
                              hipStream_t stream) {
    const float* inputs = (const float*)d_in[0];   // [8192, 512, 8] f32
    const float* params = (const float*)d_in[1];   // [13] f32
    float* out = (float*)d_out;                    // [8192, 512, 4] f32

    if (ws_size >= PACK_BYTES + SNAP_BYTES + CS_BYTES) {
        unsigned char* pk = (unsigned char*)d_ws;
        float* snap = (float*)((char*)d_ws + PACK_BYTES);
        float* cs   = (float*)((char*)d_ws + PACK_BYTES + SNAP_BYTES);
        fused_pack_affine<<<dim3(GRPS * NCH), dim3(64), 0, stream>>>(inputs, params, pk, cs);
        boundary_prefix2<<<dim3(B_ / 64), dim3(64), 0, stream>>>(cs, params, snap);
        chunk_logits<<<dim3(GRPS * NCH), dim3(64), 0, stream>>>(pk, params, snap, out);
    } else if (ws_size >= PACK_BYTES + SNAP_BYTES) {
        unsigned char* pk = (unsigned char*)d_ws;
        float* snap = (float*)((char*)d_ws + PACK_BYTES);
        pack_kernel<<<dim3((B_ * T_) / 256), dim3(256), 0, stream>>>(inputs, pk);
        seq_carry<<<dim3(GRPS), dim3(64), 0, stream>>>(pk, params, snap);
        chunk_logits<<<dim3(GRPS * NCH), dim3(64), 0, stream>>>(pk, params, snap, out);
    } else if (ws_size >= PACK_BYTES) {
        unsigned char* pk = (unsigned char*)d_ws;
        pack_kernel<<<dim3((B_ * T_) / 256), dim3(256), 0, stream>>>(inputs, pk);
        castro_scan_packed<<<dim3(GRPS), dim3(64), 0, stream>>>(pk, params, out);
    }
}